// Round 1
// baseline (279.133 us; speedup 1.0000x reference)
//
#include <hip/hip_runtime.h>
#include <stdint.h>

typedef __bf16 bf16_t;
typedef __attribute__((ext_vector_type(8))) __bf16 bf16x8;
typedef __attribute__((ext_vector_type(4))) float f32x4;

#define NDIM 4096

// ---------------------------------------------------------------------------
// BFP quantize (unchanged, harness-proven): groups of 64 share exponent of
// group max; 4 floats/thread -> 16-lane butterfly max. grid.y selects tensor.
// ---------------------------------------------------------------------------
__global__ __launch_bounds__(256) void quant_bfp(const float* __restrict__ in0,
                                                 bf16_t* __restrict__ out0,
                                                 const float* __restrict__ in1,
                                                 bf16_t* __restrict__ out1) {
    const float* in = blockIdx.y ? in1 : in0;
    bf16_t* out     = blockIdx.y ? out1 : out0;
    const int t = blockIdx.x * 256 + threadIdx.x;
    float4 v = ((const float4*)in)[t];
    float m = fmaxf(fmaxf(fabsf(v.x), fabsf(v.y)), fmaxf(fabsf(v.z), fabsf(v.w)));
    m = fmaxf(m, __shfl_xor(m, 1));
    m = fmaxf(m, __shfl_xor(m, 2));
    m = fmaxf(m, __shfl_xor(m, 4));
    m = fmaxf(m, __shfl_xor(m, 8));
    const int e = (int)((__float_as_uint(m) >> 23) & 0xFF) - 127;
    float step = __uint_as_float((uint32_t)(e + 120) << 23);  // 2^(e-7)
    float inv  = __uint_as_float((uint32_t)(134 - e) << 23);  // 2^(7-e)
    if (m == 0.0f) { step = 0.0f; inv = 0.0f; }
    float q0 = fminf(fmaxf(rintf(v.x * inv), -128.0f), 127.0f) * step;
    float q1 = fminf(fmaxf(rintf(v.y * inv), -128.0f), 127.0f) * step;
    float q2 = fminf(fmaxf(rintf(v.z * inv), -128.0f), 127.0f) * step;
    float q3 = fminf(fmaxf(rintf(v.w * inv), -128.0f), 127.0f) * step;
    union { bf16_t b[4]; uint2 u; } o;
    o.b[0] = (bf16_t)q0; o.b[1] = (bf16_t)q1;
    o.b[2] = (bf16_t)q2; o.b[3] = (bf16_t)q3;
    ((uint2*)out)[t] = o.u;
}

// ---------------------------------------------------------------------------
// GEMM, 256x256-tile 8-phase pipelined schedule (m201 template, plain HIP):
//   512 thr = 8 waves (2M x 4N), per-wave 128x64 output, BK=64,
//   LDS 128 KiB = 2 buf x (A 256x64 + B 256x64) bf16, chunk-XOR swizzle,
//   global_load_lds width-16 staging, counted vmcnt (never 0 in loop),
//   setprio(1) around each 16-MFMA cluster, XCD-chunked block remap.
// Per 2-K-tile iteration: 8 phases, each = {ds_read frags | stage 1 half-tile
// -> barrier -> MFMA quadrant -> [vmcnt] -> barrier}.
// Stage targets are regions fully consumed >=1 barrier earlier:
//   A halves of buf c consumed at ph1/ph3 of its tile -> restaged next tile's
//   ph1/ph2 (other buf); B halves consumed ph1+ph2 -> restaged same-tile
//   ph3/ph4. vmcnt(8) @ph2 guards same-tile A-h1; vmcnt(6) @ph4 guards the
//   whole next tile (3 half-tiles = 6 loads stay in flight).
// ---------------------------------------------------------------------------
__device__ __forceinline__ void g2l16(const bf16_t* g, void* l) {
    __builtin_amdgcn_global_load_lds(
        (__attribute__((address_space(1))) void*)g,
        (__attribute__((address_space(3))) void*)l, 16, 0, 0);
}

#define FENCE() asm volatile("" ::: "memory")
#define BAR()   do { FENCE(); __builtin_amdgcn_s_barrier(); FENCE(); } while (0)
#define WAITV(n) asm volatile("s_waitcnt vmcnt(" #n ")" ::: "memory")

// stage one 128x64 half-tile (2 x global_load_lds dwordx4 per thread)
#define STAGE_A(b, h, ko) do {                                                  \
    g2l16(gA + (size_t)((h) * 128) * NDIM + (ko),                               \
          (char*)sA + (b) * 32768 + (h) * 16384 + tid * 16);                    \
    g2l16(gA + (size_t)((h) * 128 + 64) * NDIM + (ko),                          \
          (char*)sA + (b) * 32768 + (h) * 16384 + 8192 + tid * 16);             \
} while (0)
#define STAGE_B(b, h, ko) do {                                                  \
    g2l16(gB + (size_t)((h) * 128) * NDIM + (ko),                               \
          (char*)sB + (b) * 32768 + (h) * 16384 + tid * 16);                    \
    g2l16(gB + (size_t)((h) * 128 + 64) * NDIM + (ko),                          \
          (char*)sB + (b) * 32768 + (h) * 16384 + 8192 + tid * 16);             \
} while (0)

// register-fragment loads (swizzled read side, proven bank-conflict-free)
#define LDA(b, qm) do {                                                         \
    _Pragma("unroll")                                                           \
    for (int i_ = 0; i_ < 4; ++i_) {                                            \
        const int r_ = (b) * 16384 + aRow + ((qm) * 64 + i_ * 16) * 64;         \
        afr[i_][0] = *(const bf16x8*)&sA[r_ + ce0];                             \
        afr[i_][1] = *(const bf16x8*)&sA[r_ + ce1];                             \
    }                                                                           \
} while (0)
#define LDB(b, qn) do {                                                         \
    _Pragma("unroll")                                                           \
    for (int j_ = 0; j_ < 2; ++j_) {                                            \
        const int r_ = (b) * 16384 + bRow + ((qn) * 32 + j_ * 16) * 64;         \
        bfr[qn][j_][0] = *(const bf16x8*)&sB[r_ + ce0];                         \
        bfr[qn][j_][1] = *(const bf16x8*)&sB[r_ + ce1];                         \
    }                                                                           \
} while (0)

// one C-quadrant x K=64: 16 MFMA, prio-boosted
#define MFMAQ(qm, qn) do {                                                      \
    __builtin_amdgcn_s_setprio(1);                                              \
    _Pragma("unroll")                                                           \
    for (int i_ = 0; i_ < 4; ++i_)                                              \
        _Pragma("unroll")                                                       \
        for (int j_ = 0; j_ < 2; ++j_) {                                        \
            acc[(qm)*4+i_][(qn)*2+j_] = __builtin_amdgcn_mfma_f32_16x16x32_bf16(\
                afr[i_][0], bfr[qn][j_][0], acc[(qm)*4+i_][(qn)*2+j_], 0, 0, 0);\
            acc[(qm)*4+i_][(qn)*2+j_] = __builtin_amdgcn_mfma_f32_16x16x32_bf16(\
                afr[i_][1], bfr[qn][j_][1], acc[(qm)*4+i_][(qn)*2+j_], 0, 0, 0);\
        }                                                                       \
    __builtin_amdgcn_s_setprio(0);                                              \
} while (0)

__global__ __launch_bounds__(512, 2) void gemm_bfp(const bf16_t* __restrict__ A,
                                                   const bf16_t* __restrict__ B,
                                                   const float* __restrict__ bias,
                                                   float* __restrict__ C) {
    __shared__ bf16_t sA[2 * 256 * 64];   // 64 KiB  [buf][row 0..255][k 0..63]
    __shared__ bf16_t sB[2 * 256 * 64];   // 64 KiB

    const int tid  = threadIdx.x;
    const int wave = tid >> 6;
    const int lane = tid & 63;
    const int wr   = wave >> 2;           // 0..1  (M)
    const int wc   = wave & 3;            // 0..3  (N)

    // XCD-chunked remap: 256 blocks, XCD x owns wg [32x, 32x+32) = 2 bm rows
    const int p  = blockIdx.x;
    const int wg = (p & 7) * 32 + (p >> 3);
    const int bm = wg >> 4;
    const int bn = wg & 15;

    // staging geometry: thread -> (row = tid>>3, chunk = tid&7), XOR-swizzled src
    const int srow = tid >> 3;
    const int swz  = ((tid & 7) ^ (srow & 7)) * 8;
    const bf16_t* gA = A + (size_t)(bm * 256 + srow) * NDIM + swz;
    const bf16_t* gB = B + (size_t)(bn * 256 + srow) * NDIM + swz;

    // read-side geometry (row == l16 mod 8 -> same swizzle key)
    const int quad = lane >> 4;
    const int l16  = lane & 15;
    const int rsw  = l16 & 7;
    const int ce0  = (quad ^ rsw) * 8;        // ks=0 chunk (elems)
    const int ce1  = ((4 + quad) ^ rsw) * 8;  // ks=32 chunk
    const int aRow = (wr * 128 + l16) * 64;   // elem base of wave's A rows
    const int bRow = (wc * 64 + l16) * 64;

    f32x4 acc[8][4];
#pragma unroll
    for (int i = 0; i < 8; ++i)
#pragma unroll
        for (int j = 0; j < 4; ++j) acc[i][j] = (f32x4){0.0f, 0.0f, 0.0f, 0.0f};

    bf16x8 afr[4][2];      // current qm half: 4 frags x 2 k-slices
    bf16x8 bfr[2][2][2];   // both qn halves live across the tile

    // prologue: tile0 A+B, tile1 B (tile1 A arrives from ph1/ph2 of tile0)
    STAGE_A(0, 0, 0); STAGE_A(0, 1, 0);
    STAGE_B(0, 0, 0); STAGE_B(0, 1, 0);
    STAGE_B(1, 0, 64); STAGE_B(1, 1, 64);
    WAITV(0);
    BAR();

    for (int kt = 0; kt < NDIM; kt += 128) {
        const int koA1 = kt + 64;                          // tile 2i+1 A (always in range)
        const int koN2 = (kt + 128 < NDIM) ? kt + 128 : 0; // tile 2i+2 A,B (dummy at tail)
        const int koB3 = (kt + 192 < NDIM) ? kt + 192 : 0; // tile 2i+3 B   (dummy at tail)

        // ---- tile 2i: compute buf0; A-stages -> buf1, B-stages -> buf0 ----
        LDA(0, 0); LDB(0, 0);            // ph1
        STAGE_A(1, 0, koA1);
        BAR();
        MFMAQ(0, 0);
        BAR();

        LDB(0, 1);                       // ph2
        STAGE_A(1, 1, koA1);
        BAR();
        MFMAQ(0, 1);
        WAITV(8);                        // guards this tile's A-h1 (read at ph3)
        BAR();

        LDA(0, 1);                       // ph3
        STAGE_B(0, 0, koN2);
        BAR();
        MFMAQ(1, 1);
        BAR();

        STAGE_B(0, 1, koN2);             // ph4
        BAR();
        MFMAQ(1, 0);
        WAITV(6);                        // guards next tile's A-h0/B-h0/B-h1
        BAR();

        // ---- tile 2i+1: compute buf1; A-stages -> buf0, B-stages -> buf1 ----
        LDA(1, 0); LDB(1, 0);            // ph5
        STAGE_A(0, 0, koN2);
        BAR();
        MFMAQ(0, 0);
        BAR();

        LDB(1, 1);                       // ph6
        STAGE_A(0, 1, koN2);
        BAR();
        MFMAQ(0, 1);
        WAITV(8);
        BAR();

        LDA(1, 1);                       // ph7
        STAGE_B(1, 0, koB3);
        BAR();
        MFMAQ(1, 1);
        BAR();

        STAGE_B(1, 1, koB3);             // ph8
        BAR();
        MFMAQ(1, 0);
        WAITV(6);
        BAR();
    }

    // epilogue: C/D layout col = lane&15, row = quad*4 + reg  [m89-verified]
    const int row0 = bm * 256 + wr * 128 + quad * 4;
    const int col0 = bn * 256 + wc * 64 + l16;
#pragma unroll
    for (int nj = 0; nj < 4; ++nj) {
        const int c = col0 + nj * 16;
        const float bv = 2.0f * bias[c];
#pragma unroll
        for (int mi = 0; mi < 8; ++mi) {
            const int r = row0 + mi * 16;
#pragma unroll
            for (int reg = 0; reg < 4; ++reg)
                C[(size_t)(r + reg) * NDIM + c] = acc[mi][nj][reg] + bv;
        }
    }
}

extern "C" void kernel_launch(void* const* d_in, const int* in_sizes, int n_in,
                              void* d_out, int out_size, void* d_ws, size_t ws_size,
                              hipStream_t stream) {
    const float* x    = (const float*)d_in[0];
    const float* w    = (const float*)d_in[1];
    const float* bias = (const float*)d_in[2];
    float* out = (float*)d_out;

    bf16_t* xq = (bf16_t*)d_ws;                         // 32 MB
    bf16_t* wq = xq + (size_t)NDIM * NDIM;              // 32 MB

    const int qblocks = (NDIM * NDIM / 4) / 256;        // 16384
    dim3 qgrid(qblocks, 2);
    quant_bfp<<<qgrid, 256, 0, stream>>>(x, xq, w, wq);

    dim3 grid(256);                                     // 16x16 tiles, 1 block/CU
    gemm_bfp<<<grid, 512, 0, stream>>>(xq, wq, bias, out);
}